// Round 5
// baseline (91.847 us; speedup 1.0000x reference)
//
#include <hip/hip_runtime.h>
#include <math.h>

#define BATCH 32
#define M 64
#define R 8
typedef unsigned long long u64;
typedef float f32x16 __attribute__((ext_vector_type(16)));

// XOR swizzle of the float4 slot within a 64-float (256 B) LDS row (G4 recipe).
#define SWZ_SLOT(r, s) ((s) ^ ((r) & 7))
#define PM_IDX(r, c) ((((r) << 6)) + ((SWZ_SLOT((r), (c) >> 2) << 2) | ((c) & 3)))

// Row register file: 64 floats in four ext-vectors (always VGPR-resident).
// i must be a compile-time constant post-unroll; dead branches fold.
#define GET_R(i) ((i) < 16 ? rv0[(i) & 15] : (i) < 32 ? rv1[(i) & 15] \
                 : (i) < 48 ? rv2[(i) & 15] : rv3[(i) & 15])
#define SET_R(i, val) do { if ((i) < 16) rv0[(i) & 15] = (val); \
    else if ((i) < 32) rv1[(i) & 15] = (val); \
    else if ((i) < 48) rv2[(i) & 15] = (val); \
    else rv3[(i) & 15] = (val); } while (0)

// (val,idx) merge, left-preference on ties -> exact first-index argmax when
// merged ranges are contiguous with left < right.
#define MERGE(av, ai, bv, bi, ov, oi) \
    { const bool c_ = ((av) >= (bv)); (ov) = c_ ? (av) : (bv); (oi) = c_ ? (ai) : (bi); }

// Wave-wide max via DPP (VALU pipe) + readlane broadcast.
__device__ __forceinline__ float wave_max_bcast(float g) {
    int v = __float_as_int(g);
    #define DPP_STEP(ctrl)                                                   \
        { int o = __builtin_amdgcn_update_dpp(v, v, (ctrl), 0xf, 0xf, false);\
          g = fmaxf(g, __int_as_float(o)); v = __float_as_int(g); }
    DPP_STEP(0x111)  // row_shr:1
    DPP_STEP(0x112)  // row_shr:2
    DPP_STEP(0x114)  // row_shr:4
    DPP_STEP(0x118)  // row_shr:8
    DPP_STEP(0x142)  // row_bcast:15
    DPP_STEP(0x143)  // row_bcast:31 -> lane 63 holds the wave max
    #undef DPP_STEP
    return __int_as_float(__builtin_amdgcn_readlane(v, 63));
}

__device__ __forceinline__ u64 readlane_u64(u64 v, int lane) {
    unsigned lo = (unsigned)__builtin_amdgcn_readlane((int)(unsigned)v, lane);
    unsigned hi = (unsigned)__builtin_amdgcn_readlane((int)(v >> 32), lane);
    return ((u64)hi << 32) | lo;
}

// One block per batch. 4 waves stage pairmax into LDS; wave 0 pulls its row
// into vector registers and runs the greedy loop with zero memory traffic;
// wave 1 computes the label score concurrently; waves 2-3 retire.
__global__ __launch_bounds__(256, 1)
void tree_crf_mst_kernel(const float* __restrict__ le,   // [B, M, M, R]
                         const int* __restrict__ tree,   // [B, M, 3]
                         float* __restrict__ mst_out,    // [B]
                         float* __restrict__ ls_out)     // [B]
{
    __shared__ __align__(16) float pm[M * M];            // 16 KB swizzled rows
    const int b = blockIdx.x;
    const int tt = threadIdx.x;
    const float* bl = le + (size_t)b * M * M * R;
    const float4* g4 = reinterpret_cast<const float4*>(bl);

    // ---- stage pairmax[r][c] = max_k le[r,c,k] (all 4 waves, coalesced) ----
    #pragma unroll
    for (int p = tt; p < M * M; p += 256) {
        const float4 a  = g4[2 * p];
        const float4 c4 = g4[2 * p + 1];
        const float mx = fmaxf(fmaxf(fmaxf(a.x, a.y), fmaxf(a.z, a.w)),
                               fmaxf(fmaxf(c4.x, c4.y), fmaxf(c4.z, c4.w)));
        const int rr = p >> 6, cc = p & 63;
        pm[PM_IDX(rr, cc)] = mx;
    }
    __syncthreads();                                     // only barrier

    const int wave = tt >> 6;
    const int t = tt & 63;

    if (wave == 1) {
        // ---- label tree score (overlaps wave 0's greedy loop) ----
        const int* tr = tree + ((size_t)b * M + t) * 3;
        const int i0 = tr[0], i1 = tr[1], i2 = tr[2];
        float ls = 0.0f;
        if (!((i0 == 0) & (i1 == 0) & (i2 == 0)))        // (0,0,0) contributes 0
            ls = bl[(size_t)((i0 << 6) | i1) * R + i2];
        #pragma unroll
        for (int off = 32; off; off >>= 1) ls += __shfl_down(ls, off);
        if (t == 0) ls_out[b] = ls;
        return;
    }
    if (wave != 0) return;

    // ---- lane t pulls row t into vector registers (logical order) ----
    f32x16 rv0, rv1, rv2, rv3;
    {
        const float4* row4 = reinterpret_cast<const float4*>(pm) + (t << 4);
        const int x = t & 7;
        #pragma unroll
        for (int s = 0; s < 16; ++s) {
            const float4 v = row4[s ^ x];
            SET_R(4 * s + 0, v.x); SET_R(4 * s + 1, v.y);
            SET_R(4 * s + 2, v.z); SET_R(4 * s + 3, v.w);
        }
    }

    u64 mask = 1ull << t;                                // partition of node t
    float mst = 0.0f;

    #pragma unroll 1                                     // keep loop rolled
    for (int it = 0; it < M; ++it) {
        // ---- row (val,idx) argmax: contiguous-pair tree, depth 6 ----
        f32x16 v0a, v0b, v1;
        typedef int i32x16 __attribute__((ext_vector_type(16)));
        i32x16 j0a, j0b, j1;
        #pragma unroll
        for (int i = 0; i < 16; ++i) {
            const float a = GET_R(2 * i), bb = GET_R(2 * i + 1);
            const bool c = (a >= bb);
            v0a[i] = c ? a : bb; j0a[i] = c ? (2 * i) : (2 * i + 1);
        }
        #pragma unroll
        for (int i = 0; i < 16; ++i) {
            const float a = GET_R(32 + 2 * i), bb = GET_R(32 + 2 * i + 1);
            const bool c = (a >= bb);
            v0b[i] = c ? a : bb; j0b[i] = c ? (32 + 2 * i) : (32 + 2 * i + 1);
        }
        #pragma unroll
        for (int i = 0; i < 8; ++i)
            MERGE(v0a[2 * i], j0a[2 * i], v0a[2 * i + 1], j0a[2 * i + 1],
                  v1[i], j1[i]);
        #pragma unroll
        for (int i = 0; i < 8; ++i)
            MERGE(v0b[2 * i], j0b[2 * i], v0b[2 * i + 1], j0b[2 * i + 1],
                  v1[8 + i], j1[8 + i]);
        float l2v[8]; int l2i[8];
        #pragma unroll
        for (int i = 0; i < 8; ++i)
            MERGE(v1[2 * i], j1[2 * i], v1[2 * i + 1], j1[2 * i + 1],
                  l2v[i], l2i[i]);
        float l3v[4]; int l3i[4];
        #pragma unroll
        for (int i = 0; i < 4; ++i)
            MERGE(l2v[2 * i], l2i[2 * i], l2v[2 * i + 1], l2i[2 * i + 1],
                  l3v[i], l3i[i]);
        float l4v0, l4v1; int l4i0, l4i1;
        MERGE(l3v[0], l3i[0], l3v[1], l3i[1], l4v0, l4i0);
        MERGE(l3v[2], l3i[2], l3v[3], l3i[3], l4v1, l4i1);
        float m; int marg;
        MERGE(l4v0, l4i0, l4v1, l4i1, m, marg);

        // ---- global max + winner (smallest row, then smallest column) ----
        const float g = wave_max_bcast(m);
        if (g == -INFINITY) break;                       // nothing left
        const u64 sel = __ballot(m == g);
        const int gi = __ffsll((long long)sel) - 1;
        const int gj = __builtin_amdgcn_readlane(marg, gi);

        mst += g;                                        // identical on all lanes
        const u64 mf = readlane_u64(mask, gi);
        const u64 mt = readlane_u64(mask, gj);
        const u64 merged = mf | mt;
        if ((merged >> t) & 1) mask = merged;

        // ---- block P x Q and Q x P (row-t slice): register cndmask kills ----
        const u64 rbm = (((mf >> t) & 1) ? mt : 0ull) |
                        (((mt >> t) & 1) ? mf : 0ull);
        const unsigned rlo = (unsigned)rbm, rhi = (unsigned)(rbm >> 32);
        #pragma unroll
        for (int j = 0; j < 16; ++j) {
            if ((rlo >> j) & 1u)        rv0[j] = -INFINITY;
            if ((rlo >> (j + 16)) & 1u) rv1[j] = -INFINITY;
            if ((rhi >> j) & 1u)        rv2[j] = -INFINITY;
            if ((rhi >> (j + 16)) & 1u) rv3[j] = -INFINITY;
        }
    }
    if (t == 0) mst_out[b] = mst;
}

// Fixed-order final reduction -> deterministic scalar output.
__global__ void tree_crf_reduce_kernel(const float* __restrict__ mst_p,
                                       const float* __restrict__ ls_p,
                                       float* __restrict__ out)
{
    if (threadIdx.x == 0 && blockIdx.x == 0) {
        float s = 0.0f;
        for (int i = 0; i < BATCH; ++i) s += mst_p[i] - ls_p[i];
        out[0] = s * (1.0f / BATCH);
    }
}

extern "C" void kernel_launch(void* const* d_in, const int* in_sizes, int n_in,
                              void* d_out, int out_size, void* d_ws, size_t ws_size,
                              hipStream_t stream) {
    const float* le   = (const float*)d_in[0];   // [32, 64, 64, 8] f32
    const int*   tree = (const int*)d_in[1];     // [32, 64, 3] i32
    float* out = (float*)d_out;                  // [1] f32
    float* mst_p = (float*)d_ws;                 // [32]
    float* ls_p  = mst_p + BATCH;                // [32]

    tree_crf_mst_kernel<<<BATCH, 256, 0, stream>>>(le, tree, mst_p, ls_p);
    tree_crf_reduce_kernel<<<1, 64, 0, stream>>>(mst_p, ls_p, out);
}

// Round 6
// 81.640 us; speedup vs baseline: 1.1250x; 1.1250x over previous
//
#include <hip/hip_runtime.h>
#include <math.h>

#define BATCH 32
#define M 64
#define R 8
typedef unsigned long long u64;

// XOR swizzle of the float4 slot within a 64-float (256 B) LDS row (G4 recipe).
#define SWZ_SLOT(r, s) ((s) ^ ((r) & 7))
#define PM_IDX(r, c) ((((r) << 6)) + ((SWZ_SLOT((r), (c) >> 2) << 2) | ((c) & 3)))

// Wave-wide max via DPP (VALU pipe) + readlane broadcast.
__device__ __forceinline__ float wave_max_bcast(float g) {
    int v = __float_as_int(g);
    #define DPP_STEP(ctrl)                                                   \
        { int o = __builtin_amdgcn_update_dpp(v, v, (ctrl), 0xf, 0xf, false);\
          g = fmaxf(g, __int_as_float(o)); v = __float_as_int(g); }
    DPP_STEP(0x111)  // row_shr:1
    DPP_STEP(0x112)  // row_shr:2
    DPP_STEP(0x114)  // row_shr:4
    DPP_STEP(0x118)  // row_shr:8
    DPP_STEP(0x142)  // row_bcast:15
    DPP_STEP(0x143)  // row_bcast:31 -> lane 63 holds the wave max
    #undef DPP_STEP
    return __int_as_float(__builtin_amdgcn_readlane(v, 63));
}

__device__ __forceinline__ u64 readlane_u64(u64 v, int lane) {
    unsigned lo = (unsigned)__builtin_amdgcn_readlane((int)(unsigned)v, lane);
    unsigned hi = (unsigned)__builtin_amdgcn_readlane((int)(v >> 32), lane);
    return ((u64)hi << 32) | lo;
}

// LDS float4 -> four named scalar registers.
#define LOADQ(s, a, b, c, d) \
    { const float4 v_ = row4[(s) ^ x]; a = v_.x; b = v_.y; c = v_.z; d = v_.w; }

// (val,idx) merge, left preference on >= : exact first-flat-index argmax for
// contiguous ranges (left range has strictly smaller indices).
#define L0(n, A, B) float v0_##n; int j0_##n; \
    { const bool c_ = r##A >= r##B; v0_##n = c_ ? r##A : r##B; j0_##n = c_ ? A : B; }
#define LN(lv, n, pv, A, B) float v##lv##_##n; int j##lv##_##n; \
    { const bool c_ = v##pv##_##A >= v##pv##_##B; \
      v##lv##_##n = c_ ? v##pv##_##A : v##pv##_##B; \
      j##lv##_##n = c_ ? j##pv##_##A : j##pv##_##B; }

#define KILL(n, w, bit) if (((w) >> (bit)) & 1u) r##n = -INFINITY;

// One block per batch. 4 waves stage pairmax into LDS; wave 0 pulls its row
// into 64 NAMED scalar registers (no arrays -> no scratch) and runs the greedy
// loop with zero memory traffic; wave 1 does the label score concurrently.
__global__ __launch_bounds__(256)
__attribute__((amdgpu_waves_per_eu(1, 1)))
void tree_crf_mst_kernel(const float* __restrict__ le,   // [B, M, M, R]
                         const int* __restrict__ tree,   // [B, M, 3]
                         float* __restrict__ mst_out,    // [B]
                         float* __restrict__ ls_out)     // [B]
{
    __shared__ __align__(16) float pm[M * M];            // 16 KB swizzled rows
    const int b = blockIdx.x;
    const int tt = threadIdx.x;
    const float* bl = le + (size_t)b * M * M * R;
    const float4* g4 = reinterpret_cast<const float4*>(bl);

    // ---- stage pairmax[r][c] = max_k le[r,c,k] (all 4 waves, coalesced) ----
    for (int p = tt; p < M * M; p += 256) {
        const float4 a  = g4[2 * p];
        const float4 c4 = g4[2 * p + 1];
        const float mx = fmaxf(fmaxf(fmaxf(a.x, a.y), fmaxf(a.z, a.w)),
                               fmaxf(fmaxf(c4.x, c4.y), fmaxf(c4.z, c4.w)));
        const int rr = p >> 6, cc = p & 63;
        pm[PM_IDX(rr, cc)] = mx;
    }
    __syncthreads();                                     // only barrier

    const int wave = tt >> 6;
    const int t = tt & 63;

    if (wave == 1) {
        // ---- label tree score (overlaps wave 0's greedy loop) ----
        const int* tr = tree + ((size_t)b * M + t) * 3;
        const int i0 = tr[0], i1 = tr[1], i2 = tr[2];
        float ls = 0.0f;
        if (!((i0 == 0) & (i1 == 0) & (i2 == 0)))        // (0,0,0) contributes 0
            ls = bl[(size_t)((i0 << 6) | i1) * R + i2];
        #pragma unroll
        for (int off = 32; off; off >>= 1) ls += __shfl_down(ls, off);
        if (t == 0) ls_out[b] = ls;
        return;
    }
    if (wave != 0) return;

    // ---- lane t pulls row t into 64 named scalar registers ----
    float r0,r1,r2,r3,r4,r5,r6,r7,r8,r9,r10,r11,r12,r13,r14,r15,
          r16,r17,r18,r19,r20,r21,r22,r23,r24,r25,r26,r27,r28,r29,r30,r31,
          r32,r33,r34,r35,r36,r37,r38,r39,r40,r41,r42,r43,r44,r45,r46,r47,
          r48,r49,r50,r51,r52,r53,r54,r55,r56,r57,r58,r59,r60,r61,r62,r63;
    {
        const float4* row4 = reinterpret_cast<const float4*>(pm) + (t << 4);
        const int x = t & 7;
        LOADQ(0,  r0,  r1,  r2,  r3)  LOADQ(1,  r4,  r5,  r6,  r7)
        LOADQ(2,  r8,  r9,  r10, r11) LOADQ(3,  r12, r13, r14, r15)
        LOADQ(4,  r16, r17, r18, r19) LOADQ(5,  r20, r21, r22, r23)
        LOADQ(6,  r24, r25, r26, r27) LOADQ(7,  r28, r29, r30, r31)
        LOADQ(8,  r32, r33, r34, r35) LOADQ(9,  r36, r37, r38, r39)
        LOADQ(10, r40, r41, r42, r43) LOADQ(11, r44, r45, r46, r47)
        LOADQ(12, r48, r49, r50, r51) LOADQ(13, r52, r53, r54, r55)
        LOADQ(14, r56, r57, r58, r59) LOADQ(15, r60, r61, r62, r63)
    }

    u64 mask = 1ull << t;                                // partition of node t
    float mst = 0.0f;

    #pragma unroll 1                                     // keep loop rolled
    for (int it = 0; it < M; ++it) {
        // ---- row (val,idx) argmax: straight-line merge tree, depth 6 ----
        L0(0,0,1)    L0(1,2,3)    L0(2,4,5)    L0(3,6,7)
        L0(4,8,9)    L0(5,10,11)  L0(6,12,13)  L0(7,14,15)
        L0(8,16,17)  L0(9,18,19)  L0(10,20,21) L0(11,22,23)
        L0(12,24,25) L0(13,26,27) L0(14,28,29) L0(15,30,31)
        L0(16,32,33) L0(17,34,35) L0(18,36,37) L0(19,38,39)
        L0(20,40,41) L0(21,42,43) L0(22,44,45) L0(23,46,47)
        L0(24,48,49) L0(25,50,51) L0(26,52,53) L0(27,54,55)
        L0(28,56,57) L0(29,58,59) L0(30,60,61) L0(31,62,63)
        LN(1,0,0,0,1)   LN(1,1,0,2,3)   LN(1,2,0,4,5)   LN(1,3,0,6,7)
        LN(1,4,0,8,9)   LN(1,5,0,10,11) LN(1,6,0,12,13) LN(1,7,0,14,15)
        LN(1,8,0,16,17) LN(1,9,0,18,19) LN(1,10,0,20,21) LN(1,11,0,22,23)
        LN(1,12,0,24,25) LN(1,13,0,26,27) LN(1,14,0,28,29) LN(1,15,0,30,31)
        LN(2,0,1,0,1)   LN(2,1,1,2,3)   LN(2,2,1,4,5)   LN(2,3,1,6,7)
        LN(2,4,1,8,9)   LN(2,5,1,10,11) LN(2,6,1,12,13) LN(2,7,1,14,15)
        LN(3,0,2,0,1)   LN(3,1,2,2,3)   LN(3,2,2,4,5)   LN(3,3,2,6,7)
        LN(4,0,3,0,1)   LN(4,1,3,2,3)
        LN(5,0,4,0,1)
        const float m = v5_0;
        const int marg = j5_0;

        // ---- global max + winner (smallest row, then smallest column) ----
        const float g = wave_max_bcast(m);
        if (g == -INFINITY) break;                       // nothing left
        const u64 sel = __ballot(m == g);
        const int gi = __ffsll((long long)sel) - 1;
        const int gj = __builtin_amdgcn_readlane(marg, gi);

        mst += g;                                        // identical on all lanes
        const u64 mf = readlane_u64(mask, gi);
        const u64 mt = readlane_u64(mask, gj);
        const u64 merged = mf | mt;
        if ((merged >> t) & 1) mask = merged;

        // ---- block P x Q and Q x P (row-t slice): register cndmask kills ----
        const u64 rbm = (((mf >> t) & 1) ? mt : 0ull) |
                        (((mt >> t) & 1) ? mf : 0ull);
        const unsigned rlo = (unsigned)rbm, rhi = (unsigned)(rbm >> 32);
        KILL(0,rlo,0)   KILL(1,rlo,1)   KILL(2,rlo,2)   KILL(3,rlo,3)
        KILL(4,rlo,4)   KILL(5,rlo,5)   KILL(6,rlo,6)   KILL(7,rlo,7)
        KILL(8,rlo,8)   KILL(9,rlo,9)   KILL(10,rlo,10) KILL(11,rlo,11)
        KILL(12,rlo,12) KILL(13,rlo,13) KILL(14,rlo,14) KILL(15,rlo,15)
        KILL(16,rlo,16) KILL(17,rlo,17) KILL(18,rlo,18) KILL(19,rlo,19)
        KILL(20,rlo,20) KILL(21,rlo,21) KILL(22,rlo,22) KILL(23,rlo,23)
        KILL(24,rlo,24) KILL(25,rlo,25) KILL(26,rlo,26) KILL(27,rlo,27)
        KILL(28,rlo,28) KILL(29,rlo,29) KILL(30,rlo,30) KILL(31,rlo,31)
        KILL(32,rhi,0)  KILL(33,rhi,1)  KILL(34,rhi,2)  KILL(35,rhi,3)
        KILL(36,rhi,4)  KILL(37,rhi,5)  KILL(38,rhi,6)  KILL(39,rhi,7)
        KILL(40,rhi,8)  KILL(41,rhi,9)  KILL(42,rhi,10) KILL(43,rhi,11)
        KILL(44,rhi,12) KILL(45,rhi,13) KILL(46,rhi,14) KILL(47,rhi,15)
        KILL(48,rhi,16) KILL(49,rhi,17) KILL(50,rhi,18) KILL(51,rhi,19)
        KILL(52,rhi,20) KILL(53,rhi,21) KILL(54,rhi,22) KILL(55,rhi,23)
        KILL(56,rhi,24) KILL(57,rhi,25) KILL(58,rhi,26) KILL(59,rhi,27)
        KILL(60,rhi,28) KILL(61,rhi,29) KILL(62,rhi,30) KILL(63,rhi,31)
    }
    if (t == 0) mst_out[b] = mst;
}

// Fixed-order final reduction -> deterministic scalar output.
__global__ void tree_crf_reduce_kernel(const float* __restrict__ mst_p,
                                       const float* __restrict__ ls_p,
                                       float* __restrict__ out)
{
    if (threadIdx.x == 0 && blockIdx.x == 0) {
        float s = 0.0f;
        for (int i = 0; i < BATCH; ++i) s += mst_p[i] - ls_p[i];
        out[0] = s * (1.0f / BATCH);
    }
}

extern "C" void kernel_launch(void* const* d_in, const int* in_sizes, int n_in,
                              void* d_out, int out_size, void* d_ws, size_t ws_size,
                              hipStream_t stream) {
    const float* le   = (const float*)d_in[0];   // [32, 64, 64, 8] f32
    const int*   tree = (const int*)d_in[1];     // [32, 64, 3] i32
    float* out = (float*)d_out;                  // [1] f32
    float* mst_p = (float*)d_ws;                 // [32]
    float* ls_p  = mst_p + BATCH;                // [32]

    tree_crf_mst_kernel<<<BATCH, 256, 0, stream>>>(le, tree, mst_p, ls_p);
    tree_crf_reduce_kernel<<<1, 64, 0, stream>>>(mst_p, ls_p, out);
}

// Round 7
// 49.604 us; speedup vs baseline: 1.8516x; 1.6459x over previous
//
#include <hip/hip_runtime.h>
#include <math.h>

#define BATCH 32
#define M 64
#define R 8
typedef unsigned long long u64;
typedef unsigned int u32;

// XOR swizzle of the float4 slot within a 64-float (256 B) LDS row (G4 recipe).
#define SWZ_SLOT(r, s) ((s) ^ ((r) & 7))
#define PM_IDX(r, c) ((((r) << 6)) + ((SWZ_SLOT((r), (c) >> 2) << 2) | ((c) & 3)))

__device__ __forceinline__ u32 umax2(u32 a, u32 b) { return a > b ? a : b; }
__device__ __forceinline__ u32 umax3(u32 a, u32 b, u32 c) {
    return umax2(umax2(a, b), c);                    // fuses to v_max3_u32
}

// Monotone f32 -> u32 map (order-preserving, total).
__device__ __forceinline__ u32 sortable(float f) {
    const u32 u = __float_as_uint(f);
    return u ^ ((u32)(((int)u) >> 31) | 0x80000000u);
}

// sign-extended bit j of w: 0xFFFFFFFF if set, else 0.
#if __has_builtin(__builtin_amdgcn_sbfe)
#define SEXTBIT(w, j) ((u32)__builtin_amdgcn_sbfe((int)(w), (j), 1))
#else
#define SEXTBIT(w, j) ((u32)(((int)((w) << (31 - (j)))) >> 31))
#endif

// masked element: packed value, or 0 if column j is blocked (blk bit set).
#define KM(j) (p##j & SEXTBIT(((j) < 32 ? nlo : nhi), (j) & 31))

// Wave-wide u32 max via DPP (VALU pipe) + readlane broadcast.
__device__ __forceinline__ u32 wave_umax_bcast(u32 g) {
    int v = (int)g;
    #define DPP_STEP(ctrl)                                                   \
        { int o = __builtin_amdgcn_update_dpp(v, v, (ctrl), 0xf, 0xf, false);\
          g = umax2(g, (u32)o); v = (int)g; }
    DPP_STEP(0x111)  // row_shr:1
    DPP_STEP(0x112)  // row_shr:2
    DPP_STEP(0x114)  // row_shr:4
    DPP_STEP(0x118)  // row_shr:8
    DPP_STEP(0x142)  // row_bcast:15
    DPP_STEP(0x143)  // row_bcast:31 -> lane 63 holds the wave max
    #undef DPP_STEP
    return (u32)__builtin_amdgcn_readlane(v, 63);
}

__device__ __forceinline__ u64 readlane_u64(u64 v, int lane) {
    unsigned lo = (unsigned)__builtin_amdgcn_readlane((int)(unsigned)v, lane);
    unsigned hi = (unsigned)__builtin_amdgcn_readlane((int)(v >> 32), lane);
    return ((u64)hi << 32) | lo;
}

// pack: 26-bit sortable value | (63 - col) in low 6 bits.
#define PK(f, j) ((sortable(f) | 63u) ^ (u32)(j))
// LDS float4 -> four named packed registers.
#define LOADP(s, a, b, c, d) { const float4 v_ = row4[(s) ^ x]; \
    p##a = PK(v_.x, a); p##b = PK(v_.y, b); p##c = PK(v_.z, c); p##d = PK(v_.w, d); }

#define T1(n, A, B, C2) const u32 a##n = umax3(KM(A), KM(B), KM(C2));

// One block per batch. 4 waves stage pairmax into LDS; wave 0 holds its row as
// 64 packed u32 registers (loop-invariant) + a cumulative blocked mask, and
// runs the greedy loop; wave 1 does the label score concurrently.
__global__ __launch_bounds__(256)
__attribute__((amdgpu_waves_per_eu(1, 1)))
void tree_crf_mst_kernel(const float* __restrict__ le,   // [B, M, M, R]
                         const int* __restrict__ tree,   // [B, M, 3]
                         float* __restrict__ mst_out,    // [B]
                         float* __restrict__ ls_out)     // [B]
{
    __shared__ __align__(16) float pm[M * M];            // 16 KB swizzled rows
    const int b = blockIdx.x;
    const int tt = threadIdx.x;
    const float* bl = le + (size_t)b * M * M * R;
    const float4* g4 = reinterpret_cast<const float4*>(bl);

    // ---- stage pairmax[r][c] = max_k le[r,c,k] (all 4 waves, coalesced) ----
    for (int q = tt; q < M * M; q += 256) {
        const float4 a  = g4[2 * q];
        const float4 c4 = g4[2 * q + 1];
        const float mx = fmaxf(fmaxf(fmaxf(a.x, a.y), fmaxf(a.z, a.w)),
                               fmaxf(fmaxf(c4.x, c4.y), fmaxf(c4.z, c4.w)));
        const int rr = q >> 6, cc = q & 63;
        pm[PM_IDX(rr, cc)] = mx;
    }
    __syncthreads();                                     // only barrier

    const int wave = tt >> 6;
    const int t = tt & 63;

    if (wave == 1) {
        // ---- label tree score (overlaps wave 0's greedy loop) ----
        const int* tr = tree + ((size_t)b * M + t) * 3;
        const int i0 = tr[0], i1 = tr[1], i2 = tr[2];
        float ls = 0.0f;
        if (!((i0 == 0) & (i1 == 0) & (i2 == 0)))        // (0,0,0) contributes 0
            ls = bl[(size_t)((i0 << 6) | i1) * R + i2];
        #pragma unroll
        for (int off = 32; off; off >>= 1) ls += __shfl_down(ls, off);
        if (t == 0) ls_out[b] = ls;
        return;
    }
    if (wave != 0) return;

    // ---- lane t: row t as 64 packed u32 named registers (loop-invariant) ----
    u32 p0,p1,p2,p3,p4,p5,p6,p7,p8,p9,p10,p11,p12,p13,p14,p15,
        p16,p17,p18,p19,p20,p21,p22,p23,p24,p25,p26,p27,p28,p29,p30,p31,
        p32,p33,p34,p35,p36,p37,p38,p39,p40,p41,p42,p43,p44,p45,p46,p47,
        p48,p49,p50,p51,p52,p53,p54,p55,p56,p57,p58,p59,p60,p61,p62,p63;
    {
        const float4* row4 = reinterpret_cast<const float4*>(pm) + (t << 4);
        const int x = t & 7;
        LOADP(0,  0,  1,  2,  3)  LOADP(1,  4,  5,  6,  7)
        LOADP(2,  8,  9,  10, 11) LOADP(3,  12, 13, 14, 15)
        LOADP(4,  16, 17, 18, 19) LOADP(5,  20, 21, 22, 23)
        LOADP(6,  24, 25, 26, 27) LOADP(7,  28, 29, 30, 31)
        LOADP(8,  32, 33, 34, 35) LOADP(9,  36, 37, 38, 39)
        LOADP(10, 40, 41, 42, 43) LOADP(11, 44, 45, 46, 47)
        LOADP(12, 48, 49, 50, 51) LOADP(13, 52, 53, 54, 55)
        LOADP(14, 56, 57, 58, 59) LOADP(15, 60, 61, 62, 63)
    }

    const u64 lanebit = 1ull << t;
    u64 mask = lanebit;                                  // partition of node t
    u64 blk = 0;                                         // blocked columns (row t)
    u32 nlo = 0xFFFFFFFFu, nhi = 0xFFFFFFFFu;            // ~blk halves
    float mst = 0.0f;

    #pragma unroll 1                                     // keep loop rolled
    for (int it = 0; it < M; ++it) {
        // ---- masked row max: 2-op mask leaves + v_max3_u32 tree, depth 4 ----
        T1(0,0,1,2)    T1(1,3,4,5)    T1(2,6,7,8)    T1(3,9,10,11)
        T1(4,12,13,14) T1(5,15,16,17) T1(6,18,19,20) T1(7,21,22,23)
        T1(8,24,25,26) T1(9,27,28,29) T1(10,30,31,32) T1(11,33,34,35)
        T1(12,36,37,38) T1(13,39,40,41) T1(14,42,43,44) T1(15,45,46,47)
        T1(16,48,49,50) T1(17,51,52,53) T1(18,54,55,56) T1(19,57,58,59)
        T1(20,60,61,62)
        const u32 a21 = KM(63);
        const u32 b0 = umax3(a0,  a1,  a2);
        const u32 b1 = umax3(a3,  a4,  a5);
        const u32 b2 = umax3(a6,  a7,  a8);
        const u32 b3 = umax3(a9,  a10, a11);
        const u32 b4 = umax3(a12, a13, a14);
        const u32 b5 = umax3(a15, a16, a17);
        const u32 b6 = umax3(a18, a19, a20);
        const u32 c0 = umax3(b0, b1, b2);
        const u32 c1 = umax3(b3, b4, b5);
        const u32 c2 = umax2(b6, a21);
        const u32 rowmax = umax3(c0, c1, c2);
        const u32 rowval = rowmax & 0xFFFFFFC0u;         // value bits only

        // ---- global max + winner (smallest row, then smallest column) ----
        const u32 gv = wave_umax_bcast(rowval);
        if (gv == 0u) break;                             // all blocked
        const u64 sel = __ballot(rowval == gv);
        const int gi = __ffsll((long long)sel) - 1;
        const u32 wp = (u32)__builtin_amdgcn_readlane((int)rowmax, gi);
        const int gj = (int)((~wp) & 63u);               // low6 = 63 - col

        mst += pm[PM_IDX(gi, gj)];                       // exact f32, uniform read

        const u64 mf = readlane_u64(mask, gi);
        const u64 mt = readlane_u64(mask, gj);
        const u64 merged = mf | mt;
        if (merged & lanebit) mask = merged;

        // ---- block P x Q and Q x P (row-t slice): cumulative bitmask only ----
        const u64 rb = ((mf & lanebit) ? mt : 0ull) | ((mt & lanebit) ? mf : 0ull);
        blk |= rb;
        nlo = ~(u32)blk;
        nhi = ~(u32)(blk >> 32);
    }
    if (t == 0) mst_out[b] = mst;
}

// Fixed-order final reduction -> deterministic scalar output.
__global__ void tree_crf_reduce_kernel(const float* __restrict__ mst_p,
                                       const float* __restrict__ ls_p,
                                       float* __restrict__ out)
{
    if (threadIdx.x == 0 && blockIdx.x == 0) {
        float s = 0.0f;
        for (int i = 0; i < BATCH; ++i) s += mst_p[i] - ls_p[i];
        out[0] = s * (1.0f / BATCH);
    }
}

extern "C" void kernel_launch(void* const* d_in, const int* in_sizes, int n_in,
                              void* d_out, int out_size, void* d_ws, size_t ws_size,
                              hipStream_t stream) {
    const float* le   = (const float*)d_in[0];   // [32, 64, 64, 8] f32
    const int*   tree = (const int*)d_in[1];     // [32, 64, 3] i32
    float* out = (float*)d_out;                  // [1] f32
    float* mst_p = (float*)d_ws;                 // [32]
    float* ls_p  = mst_p + BATCH;                // [32]

    tree_crf_mst_kernel<<<BATCH, 256, 0, stream>>>(le, tree, mst_p, ls_p);
    tree_crf_reduce_kernel<<<1, 64, 0, stream>>>(mst_p, ls_p, out);
}

// Round 8
// 47.921 us; speedup vs baseline: 1.9166x; 1.0351x over previous
//
#include <hip/hip_runtime.h>
#include <math.h>

#define BATCH 32
#define M 64
#define R 8
typedef unsigned long long u64;
typedef unsigned int u32;

// XOR swizzle of the float4 slot within a 64-float (256 B) LDS row (G4 recipe).
#define SWZ_SLOT(r, s) ((s) ^ ((r) & 7))
#define PM_IDX(r, c) ((((r) << 6)) + ((SWZ_SLOT((r), (c) >> 2) << 2) | ((c) & 3)))

__device__ __forceinline__ u32 umax2(u32 a, u32 b) { return a > b ? a : b; }
__device__ __forceinline__ u32 umax3(u32 a, u32 b, u32 c) {
    return umax2(umax2(a, b), c);                    // fuses to v_max3_u32
}

// Monotone f32 -> u32 map (order-preserving, total).
__device__ __forceinline__ u32 sortable(float f) {
    const u32 u = __float_as_uint(f);
    return u ^ ((u32)(((int)u) >> 31) | 0x80000000u);
}
// Inverse of sortable() (for a key with unknown low 6 bits, caller picks mid).
__device__ __forceinline__ float unsortable(u32 k) {
    const u32 fb = (k & 0x80000000u) ? (k ^ 0x80000000u) : ~k;
    return __uint_as_float(fb);
}

// sign-extended bit j of w: 0xFFFFFFFF if set, else 0.
#define SEXTBIT(w, j) ((u32)(((int)((w) << (31 - (j)))) >> 31))

// masked element: packed value, or 0 if column j is blocked.
#define KM(j) (p##j & SEXTBIT(((j) < 32 ? nlo : nhi), (j) & 31))

// Wave-wide u32 max: 3 max3-windowed DPP steps (16-lane rows) + 4 readlanes
// + scalar max tree. old=src, bound_ctrl=false => invalid lanes self-max.
__device__ __forceinline__ u32 wave_umax_scalar(u32 g) {
    int v = (int)g;
    const int s1a = __builtin_amdgcn_update_dpp(v, v, 0x111, 0xf, 0xf, false); // shr1
    const int s1b = __builtin_amdgcn_update_dpp(v, v, 0x112, 0xf, 0xf, false); // shr2
    const u32 t1 = umax3(g, (u32)s1a, (u32)s1b);                // window 3
    const int w = (int)t1;
    const int s2a = __builtin_amdgcn_update_dpp(w, w, 0x113, 0xf, 0xf, false); // shr3
    const int s2b = __builtin_amdgcn_update_dpp(w, w, 0x116, 0xf, 0xf, false); // shr6
    const u32 t2 = umax3(t1, (u32)s2a, (u32)s2b);               // window 9
    const int y = (int)t2;
    const int s3 = __builtin_amdgcn_update_dpp(y, y, 0x117, 0xf, 0xf, false);  // shr7
    const u32 t3 = umax2(t2, (u32)s3);                          // window 16
    const u32 a = (u32)__builtin_amdgcn_readlane((int)t3, 15);
    const u32 b = (u32)__builtin_amdgcn_readlane((int)t3, 31);
    const u32 c = (u32)__builtin_amdgcn_readlane((int)t3, 47);
    const u32 d = (u32)__builtin_amdgcn_readlane((int)t3, 63);
    return umax2(umax2(a, b), umax2(c, d));                     // scalar s_max
}

__device__ __forceinline__ u64 readlane_u64(u64 v, int lane) {
    unsigned lo = (unsigned)__builtin_amdgcn_readlane((int)(unsigned)v, lane);
    unsigned hi = (unsigned)__builtin_amdgcn_readlane((int)(v >> 32), lane);
    return ((u64)hi << 32) | lo;
}

// pack: 26-bit sortable value | (63 - col) in low 6 bits.
#define PK(f, j) ((sortable(f) | 63u) ^ (u32)(j))
// LDS float4 -> four named packed registers.
#define LOADP(s, a, b, c, d) { const float4 v_ = row4[(s) ^ x]; \
    p##a = PK(v_.x, a); p##b = PK(v_.y, b); p##c = PK(v_.z, c); p##d = PK(v_.w, d); }

#define T1(n, A, B, C2) const u32 a##n = umax3(KM(A), KM(B), KM(C2));

// One block per batch. 4 waves stage pairmax into LDS; wave 0 holds its row as
// 64 packed u32 registers (loop-invariant) + a cumulative not-blocked mask and
// runs the greedy loop with ZERO memory ops; wave 1 does the label score.
__global__ __launch_bounds__(256)
__attribute__((amdgpu_waves_per_eu(1, 1)))
void tree_crf_mst_kernel(const float* __restrict__ le,   // [B, M, M, R]
                         const int* __restrict__ tree,   // [B, M, 3]
                         float* __restrict__ mst_out,    // [B]
                         float* __restrict__ ls_out)     // [B]
{
    __shared__ __align__(16) float pm[M * M];            // 16 KB swizzled rows
    const int b = blockIdx.x;
    const int tt = threadIdx.x;
    const float* bl = le + (size_t)b * M * M * R;
    const float4* g4 = reinterpret_cast<const float4*>(bl);

    // ---- stage pairmax[r][c] = max_k le[r,c,k] (all 4 waves, coalesced) ----
    for (int q = tt; q < M * M; q += 256) {
        const float4 a  = g4[2 * q];
        const float4 c4 = g4[2 * q + 1];
        const float mx = fmaxf(fmaxf(fmaxf(a.x, a.y), fmaxf(a.z, a.w)),
                               fmaxf(fmaxf(c4.x, c4.y), fmaxf(c4.z, c4.w)));
        const int rr = q >> 6, cc = q & 63;
        pm[PM_IDX(rr, cc)] = mx;
    }
    __syncthreads();                                     // only barrier

    const int wave = tt >> 6;
    const int t = tt & 63;

    if (wave == 1) {
        // ---- label tree score (overlaps wave 0's greedy loop) ----
        const int* tr = tree + ((size_t)b * M + t) * 3;
        const int i0 = tr[0], i1 = tr[1], i2 = tr[2];
        float ls = 0.0f;
        if (!((i0 == 0) & (i1 == 0) & (i2 == 0)))        // (0,0,0) contributes 0
            ls = bl[(size_t)((i0 << 6) | i1) * R + i2];
        #pragma unroll
        for (int off = 32; off; off >>= 1) ls += __shfl_down(ls, off);
        if (t == 0) ls_out[b] = ls;
        return;
    }
    if (wave != 0) return;

    // ---- lane t: row t as 64 packed u32 named registers (loop-invariant) ----
    u32 p0,p1,p2,p3,p4,p5,p6,p7,p8,p9,p10,p11,p12,p13,p14,p15,
        p16,p17,p18,p19,p20,p21,p22,p23,p24,p25,p26,p27,p28,p29,p30,p31,
        p32,p33,p34,p35,p36,p37,p38,p39,p40,p41,p42,p43,p44,p45,p46,p47,
        p48,p49,p50,p51,p52,p53,p54,p55,p56,p57,p58,p59,p60,p61,p62,p63;
    {
        const float4* row4 = reinterpret_cast<const float4*>(pm) + (t << 4);
        const int x = t & 7;
        LOADP(0,  0,  1,  2,  3)  LOADP(1,  4,  5,  6,  7)
        LOADP(2,  8,  9,  10, 11) LOADP(3,  12, 13, 14, 15)
        LOADP(4,  16, 17, 18, 19) LOADP(5,  20, 21, 22, 23)
        LOADP(6,  24, 25, 26, 27) LOADP(7,  28, 29, 30, 31)
        LOADP(8,  32, 33, 34, 35) LOADP(9,  36, 37, 38, 39)
        LOADP(10, 40, 41, 42, 43) LOADP(11, 44, 45, 46, 47)
        LOADP(12, 48, 49, 50, 51) LOADP(13, 52, 53, 54, 55)
        LOADP(14, 56, 57, 58, 59) LOADP(15, 60, 61, 62, 63)
    }

    const u64 lanebit = 1ull << t;
    u64 mask = lanebit;                                  // partition of node t
    u32 nlo = 0xFFFFFFFFu, nhi = 0xFFFFFFFFu;            // ~blocked columns
    float mst = 0.0f;

    #pragma unroll 1                                     // keep loop rolled
    for (int it = 0; it < M; ++it) {
        // ---- masked row max: 2-op mask leaves + v_max3_u32 tree ----
        T1(0,0,1,2)    T1(1,3,4,5)    T1(2,6,7,8)    T1(3,9,10,11)
        T1(4,12,13,14) T1(5,15,16,17) T1(6,18,19,20) T1(7,21,22,23)
        T1(8,24,25,26) T1(9,27,28,29) T1(10,30,31,32) T1(11,33,34,35)
        T1(12,36,37,38) T1(13,39,40,41) T1(14,42,43,44) T1(15,45,46,47)
        T1(16,48,49,50) T1(17,51,52,53) T1(18,54,55,56) T1(19,57,58,59)
        T1(20,60,61,62)
        const u32 a21 = KM(63);
        const u32 b0 = umax3(a0,  a1,  a2);
        const u32 b1 = umax3(a3,  a4,  a5);
        const u32 b2 = umax3(a6,  a7,  a8);
        const u32 b3 = umax3(a9,  a10, a11);
        const u32 b4 = umax3(a12, a13, a14);
        const u32 b5 = umax3(a15, a16, a17);
        const u32 b6 = umax3(a18, a19, a20);
        const u32 c0 = umax3(b0, b1, b2);
        const u32 c1 = umax3(b3, b4, b5);
        const u32 c2 = umax2(b6, a21);
        const u32 rowmax = umax3(c0, c1, c2);
        const u32 rowval = rowmax & 0xFFFFFFC0u;         // value bits only

        // ---- global max + winner (smallest row, then smallest column) ----
        const u32 gv = wave_umax_scalar(rowval);
        if (gv == 0u) break;                             // all blocked
        const u64 sel = __ballot(rowval == gv);
        const int gi = __ffsll((long long)sel) - 1;
        const u32 wp = (u32)__builtin_amdgcn_readlane((int)rowmax, gi);
        const int gj = (int)((~wp) & 63u);               // low6 = 63 - col

        mst += unsortable(gv | 32u);                     // mid of lost low bits

        const u64 mf = readlane_u64(mask, gi);
        const u64 mt = readlane_u64(mask, gj);
        const u64 merged = mf | mt;
        if (merged & lanebit) mask = merged;

        // ---- block P x Q and Q x P (row-t slice): cumulative bitmask only ----
        const u64 rb = ((mf & lanebit) ? mt : 0ull) | ((mt & lanebit) ? mf : 0ull);
        nlo &= ~(u32)rb;
        nhi &= ~(u32)(rb >> 32);
    }
    if (t == 0) mst_out[b] = mst;
}

// Fixed-order final reduction -> deterministic scalar output.
__global__ void tree_crf_reduce_kernel(const float* __restrict__ mst_p,
                                       const float* __restrict__ ls_p,
                                       float* __restrict__ out)
{
    if (threadIdx.x == 0 && blockIdx.x == 0) {
        float s = 0.0f;
        for (int i = 0; i < BATCH; ++i) s += mst_p[i] - ls_p[i];
        out[0] = s * (1.0f / BATCH);
    }
}

extern "C" void kernel_launch(void* const* d_in, const int* in_sizes, int n_in,
                              void* d_out, int out_size, void* d_ws, size_t ws_size,
                              hipStream_t stream) {
    const float* le   = (const float*)d_in[0];   // [32, 64, 64, 8] f32
    const int*   tree = (const int*)d_in[1];     // [32, 64, 3] i32
    float* out = (float*)d_out;                  // [1] f32
    float* mst_p = (float*)d_ws;                 // [32]
    float* ls_p  = mst_p + BATCH;                // [32]

    tree_crf_mst_kernel<<<BATCH, 256, 0, stream>>>(le, tree, mst_p, ls_p);
    tree_crf_reduce_kernel<<<1, 64, 0, stream>>>(mst_p, ls_p, out);
}